// Round 2
// baseline (687.594 us; speedup 1.0000x reference)
//
#include <hip/hip_runtime.h>

#define BATCH 64
#define NPTS  4096
#define LIG   64
#define DIM   512
#define OUTF  7
#define TOPK  10

using ull = unsigned long long;

__device__ __forceinline__ ull shfl_down_u64(ull v, int off) {
    unsigned int lo = (unsigned int)v, hi = (unsigned int)(v >> 32);
    lo = __shfl_down(lo, off);
    hi = __shfl_down(hi, off);
    return ((ull)hi << 32) | lo;
}

__device__ __forceinline__ float dot4(float4 a, float4 b) {
    return a.x * b.x + a.y * b.y + a.z * b.z + a.w * b.w;
}

// ---------------------------------------------------------------------------
// Kernel 1: per (b, ligand-atom) find 10 nearest of 4096 points.
// Thread t owns points t*16..t*16+15 (192 contiguous bytes = 12 float4).
// Key = (f32bits(d^2) << 32) | n : u64-min == top_k stable lowest-index tie.
// Winners written to idxbuf[b][l][r].
// ---------------------------------------------------------------------------
__global__ __launch_bounds__(256) void k_topk(
    const float* __restrict__ pos,
    const float* __restrict__ lig,
    int* __restrict__ idxbuf) {
    const int l = blockIdx.x;
    const int b = blockIdx.y;
    const int t = threadIdx.x;

    const float* lp = lig + ((size_t)b * LIG + l) * 3;
    const float lx = lp[0], ly = lp[1], lz = lp[2];

    const float4* src = (const float4*)(pos + (size_t)b * NPTS * 3) + t * 12;
    float w[48];
#pragma unroll
    for (int q = 0; q < 12; ++q) {
        float4 v = src[q];
        w[4 * q] = v.x; w[4 * q + 1] = v.y; w[4 * q + 2] = v.z; w[4 * q + 3] = v.w;
    }

    ull key[16];
#pragma unroll
    for (int i = 0; i < 16; ++i) {
        float dx = w[3 * i]     - lx;
        float dy = w[3 * i + 1] - ly;
        float dz = w[3 * i + 2] - lz;
        float d2 = dx * dx + dy * dy + dz * dz;
        key[i] = ((ull)__float_as_uint(d2) << 32) | (unsigned)(t * 16 + i);
    }

    __shared__ ull red[4];
    __shared__ unsigned int widx_sh;
    const int wave = t >> 6, lane = t & 63;

    for (int r = 0; r < TOPK; ++r) {
        ull k = key[0];
#pragma unroll
        for (int i = 1; i < 16; ++i) k = (key[i] < k) ? key[i] : k;
#pragma unroll
        for (int off = 32; off > 0; off >>= 1) {
            ull o = shfl_down_u64(k, off);
            k = (o < k) ? o : k;
        }
        if (lane == 0) red[wave] = k;
        __syncthreads();
        if (t == 0) {
            ull m = red[0];
#pragma unroll
            for (int i = 1; i < 4; ++i) m = (red[i] < m) ? red[i] : m;
            unsigned int widx = (unsigned int)m;
            widx_sh = widx;
            idxbuf[((size_t)b * LIG + l) * TOPK + r] = (int)widx;
        }
        __syncthreads();
        const unsigned int widx = widx_sh;
#pragma unroll
        for (int i = 0; i < 16; ++i)
            if (widx == (unsigned)(t * 16 + i)) key[i] = ~0ull;
    }
}

// ---------------------------------------------------------------------------
// Kernel 2: per batch, dedup 640 indices via LDS bitmask, mean of selected
// x rows. grid (2, BATCH): block c covers features c*256..c*256+255, one
// float per thread (coalesced 1KB segments). 4-way unroll keeps 4
// independent loads in flight (low occupancy: only 128 blocks).
// ---------------------------------------------------------------------------
__global__ __launch_bounds__(256) void k_pool(
    const int* __restrict__ idxbuf,
    const float* __restrict__ x,
    float* __restrict__ emb) {
    const int c = blockIdx.x;
    const int b = blockIdx.y;
    const int t = threadIdx.x;

    __shared__ unsigned mword[NPTS / 32];   // 4096-bit dedup mask
    __shared__ int list[LIG * TOPK];
    __shared__ int cnt;
    if (t == 0) cnt = 0;
    for (int i = t; i < NPTS / 32; i += 256) mword[i] = 0u;
    __syncthreads();

    const int* ib = idxbuf + (size_t)b * LIG * TOPK;
    for (int j = t; j < LIG * TOPK; j += 256) {
        int idx = ib[j];
        unsigned bit = 1u << (idx & 31);
        unsigned old = atomicOr(&mword[idx >> 5], bit);
        if (!(old & bit)) list[atomicAdd(&cnt, 1)] = idx;
    }
    __syncthreads();
    const int n_sel = cnt;
    const float inv = 1.0f / (float)n_sel;

    const float* xb = x + (size_t)b * NPTS * DIM + c * 256 + t;
    float a = 0.f;
    int j = 0;
    for (; j + 4 <= n_sel; j += 4) {
        int n0 = list[j], n1 = list[j + 1], n2 = list[j + 2], n3 = list[j + 3];
        float v0 = xb[(size_t)n0 * DIM];
        float v1 = xb[(size_t)n1 * DIM];
        float v2 = xb[(size_t)n2 * DIM];
        float v3 = xb[(size_t)n3 * DIM];
        a += v0 + v1 + v2 + v3;
    }
    for (; j < n_sel; ++j) a += xb[(size_t)list[j] * DIM];

    emb[(size_t)b * DIM + c * 256 + t] = a * inv;
}

// ---------------------------------------------------------------------------
// Kernel 3: h[b,j] = emb[b,:] . W1[j,:] + b1[j].  Wave-per-row dots:
// lane covers 8 contiguous d via two float4 of W1 (coalesced 2KB/row).
// grid (8, BATCH): blockIdx.x = 64-row chunk. 4 waves x 16 rows.
// ---------------------------------------------------------------------------
__global__ __launch_bounds__(256) void k_fc1(
    const float* __restrict__ emb,
    const float* __restrict__ W1,
    const float* __restrict__ b1,
    float* __restrict__ h) {
    const int jc = blockIdx.x;
    const int b  = blockIdx.y;
    const int t  = threadIdx.x;
    const int wave = t >> 6, lane = t & 63;

    const float4* ep = (const float4*)(emb + (size_t)b * DIM) + lane * 2;
    float4 e0 = ep[0], e1 = ep[1];

#pragma unroll
    for (int q = 0; q < 16; ++q) {
        const int jj = jc * 64 + wave * 16 + q;
        const float4* wp = (const float4*)(W1 + (size_t)jj * DIM) + lane * 2;
        float s = dot4(wp[0], e0) + dot4(wp[1], e1);
#pragma unroll
        for (int off = 32; off > 0; off >>= 1) s += __shfl_down(s, off);
        if (lane == 0) h[(size_t)b * DIM + jj] = s + b1[jj];
    }
}

// ---------------------------------------------------------------------------
// Kernel 4: BatchNorm1d (training stats, biased var over B=64) + SiLU.
// 1 block, 512 threads, thread = feature. Coalesced column reads.
// ---------------------------------------------------------------------------
__global__ __launch_bounds__(512) void k_bn(
    const float* __restrict__ h,
    const float* __restrict__ gamma,
    const float* __restrict__ beta,
    float* __restrict__ hs) {
    const int jf = threadIdx.x;
    float s = 0.f, ss = 0.f;
#pragma unroll 8
    for (int b = 0; b < BATCH; ++b) {
        float v = h[(size_t)b * DIM + jf];
        s += v; ss += v * v;
    }
    const float mu  = s * (1.0f / BATCH);
    const float var = ss * (1.0f / BATCH) - mu * mu;
    const float inv = rsqrtf(var + 1e-5f);
    const float g  = gamma[jf];
    const float be = beta[jf];
#pragma unroll 8
    for (int b = 0; b < BATCH; ++b) {
        float v = h[(size_t)b * DIM + jf];
        float u = g * (v - mu) * inv + be;
        hs[(size_t)b * DIM + jf] = u / (1.0f + __expf(-u));   // u * sigmoid(u)
    }
}

// ---------------------------------------------------------------------------
// Kernel 5: out[b,o] = hs[b,:] . W2[o,:] + b2[o].
// One wave per batch row; 7 dots of 512.
// ---------------------------------------------------------------------------
__global__ __launch_bounds__(64) void k_fc2(
    const float* __restrict__ hs,
    const float* __restrict__ W2,
    const float* __restrict__ b2,
    float* __restrict__ out) {
    const int b = blockIdx.x;
    const int lane = threadIdx.x;
    const float4* hp = (const float4*)(hs + (size_t)b * DIM) + lane * 2;
    float4 h0 = hp[0], h1 = hp[1];
#pragma unroll
    for (int o = 0; o < OUTF; ++o) {
        const float4* wp = (const float4*)(W2 + (size_t)o * DIM) + lane * 2;
        float s = dot4(wp[0], h0) + dot4(wp[1], h1);
#pragma unroll
        for (int off = 32; off > 0; off >>= 1) s += __shfl_down(s, off);
        if (lane == 0) out[(size_t)b * OUTF + o] = s + b2[o];
    }
}

extern "C" void kernel_launch(void* const* d_in, const int* in_sizes, int n_in,
                              void* d_out, int out_size, void* d_ws, size_t ws_size,
                              hipStream_t stream) {
    const float* pos   = (const float*)d_in[0];
    const float* x     = (const float*)d_in[1];
    const float* lig   = (const float*)d_in[2];
    const float* W1    = (const float*)d_in[3];
    const float* b1    = (const float*)d_in[4];
    const float* gamma = (const float*)d_in[5];
    const float* beta  = (const float*)d_in[6];
    const float* W2    = (const float*)d_in[7];
    const float* b2    = (const float*)d_in[8];
    float* out = (float*)d_out;

    char* ws = (char*)d_ws;
    int*   idxbuf = (int*)ws;                                       // B*L*K ints = 160 KB
    float* emb    = (float*)(ws + (size_t)BATCH * LIG * TOPK * 4);  // B*D f32
    float* h      = emb + BATCH * DIM;                              // B*D f32
    float* hs     = h + BATCH * DIM;                                // B*D f32

    k_topk<<<dim3(LIG, BATCH), 256, 0, stream>>>(pos, lig, idxbuf);
    k_pool<<<dim3(2, BATCH), 256, 0, stream>>>(idxbuf, x, emb);
    k_fc1 <<<dim3(8, BATCH), 256, 0, stream>>>(emb, W1, b1, h);
    k_bn  <<<1, 512, 0, stream>>>(h, gamma, beta, hs);
    k_fc2 <<<BATCH, 64, 0, stream>>>(hs, W2, b2, out);
}